// Round 1
// baseline (267.610 us; speedup 1.0000x reference)
//
#include <hip/hip_runtime.h>

typedef __bf16 bf16x8 __attribute__((ext_vector_type(8)));
typedef __bf16 bf16x4 __attribute__((ext_vector_type(4)));
typedef float  f32x4  __attribute__((ext_vector_type(4)));

#define DEVINL __device__ __forceinline__

DEVINL void gload_lds16(const void* g, void* l) {
  __builtin_amdgcn_global_load_lds((const __attribute__((address_space(1))) void*)g,
                                   (__attribute__((address_space(3))) void*)l, 16, 0, 0);
}

// ---------------- RMSNorm over hidden=1024 + cast to bf16 ----------------
__global__ __launch_bounds__(256) void rmsnorm_cast_kernel(
    const float* __restrict__ X, const float* __restrict__ W, __bf16* __restrict__ Y) {
  int row = blockIdx.x, tid = threadIdx.x;
  const float4* xr = (const float4*)(X + (size_t)row * 1024);
  float4 v = xr[tid];
  float ss = v.x * v.x + v.y * v.y + v.z * v.z + v.w * v.w;
#pragma unroll
  for (int m = 1; m < 64; m <<= 1) ss += __shfl_xor(ss, m);
  __shared__ float part[4];
  if ((tid & 63) == 0) part[tid >> 6] = ss;
  __syncthreads();
  float tot = part[0] + part[1] + part[2] + part[3];
  float rn = rsqrtf(tot * (1.0f / 1024.0f) + 1e-6f);
  float4 wv = ((const float4*)W)[tid];
  bf16x4 y;
  y[0] = (__bf16)(v.x * rn * wv.x);
  y[1] = (__bf16)(v.y * rn * wv.y);
  y[2] = (__bf16)(v.z * rn * wv.z);
  y[3] = (__bf16)(v.w * rn * wv.w);
  *(bf16x4*)(Y + (size_t)row * 1024 + tid * 4) = y;
}

// ---------------- cast 4 weight matrices (1024x1024 each) to bf16 ----------------
__global__ __launch_bounds__(256) void cast_w_kernel(
    const float* __restrict__ a, const float* __restrict__ b,
    const float* __restrict__ c, const float* __restrict__ d,
    __bf16* __restrict__ oa, __bf16* __restrict__ ob,
    __bf16* __restrict__ oc, __bf16* __restrict__ od) {
  int gid = blockIdx.x * 256 + threadIdx.x;  // 524288 threads, 8 elems each
  int which = gid >> 17;
  size_t off = (size_t)(gid & 131071) * 8;
  const float* s = (which == 0) ? a : (which == 1) ? b : (which == 2) ? c : d;
  __bf16* o = (which == 0) ? oa : (which == 1) ? ob : (which == 2) ? oc : od;
  float4 v0 = *(const float4*)(s + off), v1 = *(const float4*)(s + off + 4);
  bf16x8 y;
  y[0] = (__bf16)v0.x; y[1] = (__bf16)v0.y; y[2] = (__bf16)v0.z; y[3] = (__bf16)v0.w;
  y[4] = (__bf16)v1.x; y[5] = (__bf16)v1.y; y[6] = (__bf16)v1.z; y[7] = (__bf16)v1.w;
  *(bf16x8*)(o + off) = y;
}

// ---------------- 128x128 tile bf16 GEMM, C = A @ W^T + bias (B^T layout) ----------------
// A: (M,1024) bf16 row-major ; Bw: (1024,1024) bf16 row-major = W[n][k]
// EPI=0: Cout bf16 ; EPI=1: Cout f32 = resid + alpha * (acc + bias)
template <int EPI>
__global__ __launch_bounds__(256) void gemm_bt_kernel(
    const __bf16* __restrict__ A, const __bf16* __restrict__ Bw,
    const float* __restrict__ bias, void* __restrict__ Cout,
    const float* __restrict__ resid, const float* __restrict__ alphap) {
  __shared__ __attribute__((aligned(16))) __bf16 As[128 * 32];
  __shared__ __attribute__((aligned(16))) __bf16 Bs[128 * 32];
  int tid = threadIdx.x, lane = tid & 63, w = tid >> 6, wr = w >> 1, wc = w & 1;
  int m0 = blockIdx.x * 128, n0 = blockIdx.y * 128;
  f32x4 z4 = {0.f, 0.f, 0.f, 0.f};
  f32x4 acc[4][4];
#pragma unroll
  for (int i = 0; i < 4; i++)
#pragma unroll
    for (int j = 0; j < 4; j++) acc[i][j] = z4;

  for (int k0 = 0; k0 < 1024; k0 += 32) {
#pragma unroll
    for (int i = 0; i < 2; i++) {
      int chunk = i * 256 + tid;
      int row = chunk >> 2, cc = chunk & 3;
      gload_lds16(A + (size_t)(m0 + row) * 1024 + k0 + cc * 8, (char*)As + i * 4096 + w * 1024);
      gload_lds16(Bw + (size_t)(n0 + row) * 1024 + k0 + cc * 8, (char*)Bs + i * 4096 + w * 1024);
    }
    __syncthreads();
    bf16x8 af[4], bfr[4];
#pragma unroll
    for (int m = 0; m < 4; m++) {
      int r = wr * 64 + m * 16 + (lane & 15);
      af[m] = *(const bf16x8*)((const char*)As + r * 64 + ((lane >> 4) << 4));
    }
#pragma unroll
    for (int n = 0; n < 4; n++) {
      int r = wc * 64 + n * 16 + (lane & 15);
      bfr[n] = *(const bf16x8*)((const char*)Bs + r * 64 + ((lane >> 4) << 4));
    }
#pragma unroll
    for (int m = 0; m < 4; m++)
#pragma unroll
      for (int n = 0; n < 4; n++)
        acc[m][n] = __builtin_amdgcn_mfma_f32_16x16x32_bf16(af[m], bfr[n], acc[m][n], 0, 0, 0);
    __syncthreads();
  }

  float aval = (EPI == 1) ? alphap[0] : 0.f;
#pragma unroll
  for (int m = 0; m < 4; m++)
#pragma unroll
    for (int n = 0; n < 4; n++) {
      int col = n0 + wc * 64 + n * 16 + (lane & 15);
      float bv = bias[col];
#pragma unroll
      for (int r = 0; r < 4; r++) {
        int row = m0 + wr * 64 + m * 16 + ((lane >> 4) << 2) + r;
        size_t idx = ((size_t)row << 10) + col;
        float v = acc[m][n][r] + bv;
        if (EPI == 0)
          ((__bf16*)Cout)[idx] = (__bf16)v;
        else
          ((float*)Cout)[idx] = resid[idx] + aval * v;
      }
    }
}

// ---------------- per-head RMSNorm + RoPE (+ optional 1/8 scale), bf16 in/out ----------------
// X: (B*L, 1024) bf16 token-major ; Y: (B, 16, L, 64) bf16 head-major
__global__ __launch_bounds__(256) void headnorm_rope_kernel(
    const __bf16* __restrict__ X, const float* __restrict__ HW,
    const float* __restrict__ COS, const float* __restrict__ SIN,
    __bf16* __restrict__ Y, int log2L, float scale) {
  int tid = threadIdx.x;
  int inst = blockIdx.x * 32 + (tid >> 3);  // (token, head) instance
  int sub = tid & 7;
  int token = inst >> 4, h = inst & 15;
  int L = 1 << log2L;
  int b = token >> log2L, pos = token & (L - 1);
  const __bf16* xp = X + ((size_t)token << 10) + h * 64 + sub * 8;
  bf16x8 xv = *(const bf16x8*)xp;
  float xf[8];
#pragma unroll
  for (int i = 0; i < 8; i++) xf[i] = (float)xv[i];
  float ss = 0.f;
#pragma unroll
  for (int i = 0; i < 8; i++) ss += xf[i] * xf[i];
  ss += __shfl_xor(ss, 1);
  ss += __shfl_xor(ss, 2);
  ss += __shfl_xor(ss, 4);
  float rn = rsqrtf(ss * (1.0f / 64.0f) + 1e-6f);
  const float* hwp = HW + sub * 8;
  const float* cp = COS + ((size_t)pos << 6) + sub * 8;
  const float* sp = SIN + ((size_t)pos << 6) + sub * 8;
  float xn[8], o[8];
#pragma unroll
  for (int i = 0; i < 8; i++) xn[i] = xf[i] * rn * hwp[i];
#pragma unroll
  for (int i = 0; i < 8; i += 2) {
    float c0 = cp[i], c1 = cp[i + 1], s0 = sp[i], s1 = sp[i + 1];
    o[i] = (xn[i] * c0 - xn[i + 1] * s0) * scale;
    o[i + 1] = (xn[i + 1] * c1 + xn[i] * s1) * scale;
  }
  bf16x8 yv;
#pragma unroll
  for (int i = 0; i < 8; i++) yv[i] = (__bf16)o[i];
  *(bf16x8*)(Y + (((size_t)((b << 4) + h) << log2L) + pos) * 64 + sub * 8) = yv;
}

// ---------------- V transpose: (B*Lc,1024) token-major -> (B,16,64,Lc) ----------------
__global__ __launch_bounds__(256) void v_transpose_kernel(
    const __bf16* __restrict__ V, __bf16* __restrict__ Vt) {
  int bx = blockIdx.x;
  int bh = bx >> 4;
  int j0 = (bx & 15) * 64;
  int b = bh >> 4, h = bh & 15;
  int tid = threadIdx.x;
#pragma unroll
  for (int it = 0; it < 2; ++it) {
    int c = it * 256 + tid;  // 0..511
    int jl = c >> 3, d0 = (c & 7) * 8;
    bf16x8 v = *(const bf16x8*)(V + (size_t)(b * 1024 + j0 + jl) * 1024 + h * 64 + d0);
#pragma unroll
    for (int i = 0; i < 8; i++)
      Vt[((size_t)bh * 64 + d0 + i) * 1024 + j0 + jl] = v[i];
  }
}

// ---------------- flash attention: per block 128 q-rows of one (b,h) ----------------
// Qr: (B,16,4096,64) bf16 (pre-scaled by 0.125) ; Kr: (B,16,1024,64) ; Vtr: (B,16,64,1024)
// AO: (B,4096,1024) bf16 token-major
__global__ __launch_bounds__(256) void attn_kernel(
    const __bf16* __restrict__ Qr, const __bf16* __restrict__ Kr,
    const __bf16* __restrict__ Vtr, __bf16* __restrict__ AO) {
  const float L2E = 1.44269504088896340736f;
  int tid = threadIdx.x, lane = tid & 63, w = tid >> 6;
  int q0 = blockIdx.x * 128;
  int bh = blockIdx.y, b = bh >> 4, h = bh & 15;
  __shared__ __attribute__((aligned(16))) __bf16 Qs[128 * 64];
  __shared__ __attribute__((aligned(16))) __bf16 Ks[64 * 64];
  __shared__ __attribute__((aligned(16))) __bf16 Vs[64 * 64];
  __shared__ __attribute__((aligned(16))) __bf16 Ps[4][32 * 64];

  // stage Q tile (XOR-swizzled via inverse-swizzled global source, rule #21)
  const __bf16* qbase = Qr + ((size_t)bh * 4096 + q0) * 64;
#pragma unroll
  for (int i = 0; i < 4; i++) {
    int chunk = i * 256 + tid, row = chunk >> 3, cl = (chunk & 7) ^ (row & 7);
    gload_lds16(qbase + row * 64 + cl * 8, (char*)Qs + i * 4096 + w * 1024);
  }
  f32x4 z4 = {0.f, 0.f, 0.f, 0.f};
  f32x4 acc_o[4][2];
#pragma unroll
  for (int i = 0; i < 4; i++) { acc_o[i][0] = z4; acc_o[i][1] = z4; }
  float mrun[2][4], srun[2][4];
#pragma unroll
  for (int m = 0; m < 2; m++)
#pragma unroll
    for (int r = 0; r < 4; r++) { mrun[m][r] = -3.0e38f; srun[m][r] = 0.f; }
  char* PsW = (char*)(&Ps[w][0]);
  int lg = ((lane & 15) >> 2) << 4;  // source lane for stats exchange
  int rr = lane & 3;

  for (int t = 0; t < 16; t++) {
    const __bf16* kbase = Kr + ((size_t)bh * 1024 + t * 64) * 64;
    const __bf16* vbase = Vtr + (size_t)bh * 64 * 1024 + t * 64;
#pragma unroll
    for (int i = 0; i < 2; i++) {
      int chunk = i * 256 + tid, row = chunk >> 3, cl = (chunk & 7) ^ (row & 7);
      gload_lds16(kbase + row * 64 + cl * 8, (char*)Ks + i * 4096 + w * 1024);
      gload_lds16(vbase + (size_t)row * 1024 + cl * 8, (char*)Vs + i * 4096 + w * 1024);
    }
    __syncthreads();

    // S = Q K^T  (each wave: 32 q-rows x 64 cols)
    f32x4 accs[2][4];
#pragma unroll
    for (int m = 0; m < 2; m++)
#pragma unroll
      for (int n = 0; n < 4; n++) accs[m][n] = z4;
#pragma unroll
    for (int ks = 0; ks < 2; ks++) {
      bf16x8 aq[2], bk[4];
#pragma unroll
      for (int m = 0; m < 2; m++) {
        int row = w * 32 + m * 16 + (lane & 15);
        aq[m] = *(const bf16x8*)((const char*)Qs +
                 ((row * 128 + ks * 64 + ((lane >> 4) << 4)) ^ ((row & 7) << 4)));
      }
#pragma unroll
      for (int n = 0; n < 4; n++) {
        int row = n * 16 + (lane & 15);
        bk[n] = *(const bf16x8*)((const char*)Ks +
                ((row * 128 + ks * 64 + ((lane >> 4) << 4)) ^ ((row & 7) << 4)));
      }
#pragma unroll
      for (int m = 0; m < 2; m++)
#pragma unroll
        for (int n = 0; n < 4; n++)
          accs[m][n] = __builtin_amdgcn_mfma_f32_16x16x32_bf16(aq[m], bk[n], accs[m][n], 0, 0, 0);
    }

    // online softmax (rows live in C-layout: row = m*16 + (lane>>4)*4 + r)
    float scl[2][4];
#pragma unroll
    for (int m = 0; m < 2; m++)
#pragma unroll
      for (int r = 0; r < 4; r++) {
        float mt = fmaxf(fmaxf(accs[m][0][r], accs[m][1][r]), fmaxf(accs[m][2][r], accs[m][3][r]));
        mt = fmaxf(mt, __shfl_xor(mt, 1));
        mt = fmaxf(mt, __shfl_xor(mt, 2));
        mt = fmaxf(mt, __shfl_xor(mt, 4));
        mt = fmaxf(mt, __shfl_xor(mt, 8));
        float mnew = fmaxf(mrun[m][r], mt);
        float sc = exp2f((mrun[m][r] - mnew) * L2E);
        mrun[m][r] = mnew;
        scl[m][r] = sc;
        float rs = 0.f;
#pragma unroll
        for (int n = 0; n < 4; n++) {
          float pv = exp2f((accs[m][n][r] - mnew) * L2E);
          accs[m][n][r] = pv;
          rs += pv;
        }
        rs += __shfl_xor(rs, 1);
        rs += __shfl_xor(rs, 2);
        rs += __shfl_xor(rs, 4);
        rs += __shfl_xor(rs, 8);
        srun[m][r] = srun[m][r] * sc + rs;
      }

    // write P (bf16) into per-wave LDS region, swizzled
#pragma unroll
    for (int m = 0; m < 2; m++)
#pragma unroll
      for (int n = 0; n < 4; n++)
#pragma unroll
        for (int r = 0; r < 4; r++) {
          int ql = m * 16 + ((lane >> 4) << 2) + r;
          int jb = (n * 16 + (lane & 15)) * 2;
          *(__bf16*)(PsW + ((ql * 128 + jb) ^ ((ql & 7) << 4))) = (__bf16)accs[m][n][r];
        }

    // redistribute per-row rescale factor into q-major (col) layout
    float scq[2];
#pragma unroll
    for (int qf = 0; qf < 2; qf++) {
      float v0 = __shfl(scl[qf][0], lg);
      float v1 = __shfl(scl[qf][1], lg);
      float v2 = __shfl(scl[qf][2], lg);
      float v3 = __shfl(scl[qf][3], lg);
      scq[qf] = (rr == 0) ? v0 : (rr == 1) ? v1 : (rr == 2) ? v2 : v3;
    }
#pragma unroll
    for (int df = 0; df < 4; df++) {
      acc_o[df][0] *= scq[0];
      acc_o[df][1] *= scq[1];
    }

    // O^T += V^T P^T   (A = Vt rows d, B = P read as [q][j] contiguous)
#pragma unroll
    for (int ks = 0; ks < 2; ks++) {
      bf16x8 pf[2], vf[4];
#pragma unroll
      for (int qf = 0; qf < 2; qf++) {
        int ql = qf * 16 + (lane & 15);
        pf[qf] = *(const bf16x8*)(PsW +
                 ((ql * 128 + ks * 64 + ((lane >> 4) << 4)) ^ ((ql & 7) << 4)));
      }
#pragma unroll
      for (int df = 0; df < 4; df++) {
        int dl = df * 16 + (lane & 15);
        vf[df] = *(const bf16x8*)((const char*)Vs +
                 ((dl * 128 + ks * 64 + ((lane >> 4) << 4)) ^ ((dl & 7) << 4)));
      }
#pragma unroll
      for (int df = 0; df < 4; df++)
#pragma unroll
        for (int qf = 0; qf < 2; qf++)
          acc_o[df][qf] = __builtin_amdgcn_mfma_f32_16x16x32_bf16(vf[df], pf[qf], acc_o[df][qf], 0, 0, 0);
    }
    __syncthreads();
  }

  // final 1/denominator per q (col layout)
  float dq[2];
#pragma unroll
  for (int qf = 0; qf < 2; qf++) {
    float v0 = __shfl(srun[qf][0], lg);
    float v1 = __shfl(srun[qf][1], lg);
    float v2 = __shfl(srun[qf][2], lg);
    float v3 = __shfl(srun[qf][3], lg);
    float v = (rr == 0) ? v0 : (rr == 1) ? v1 : (rr == 2) ? v2 : v3;
    dq[qf] = 1.0f / v;
  }
  // stage O through per-wave LDS for coalesced global stores
#pragma unroll
  for (int df = 0; df < 4; df++)
#pragma unroll
    for (int qf = 0; qf < 2; qf++)
#pragma unroll
      for (int r = 0; r < 4; r++) {
        int ql = qf * 16 + (lane & 15);
        int d = df * 16 + ((lane >> 4) << 2) + r;
        *(__bf16*)(PsW + ((ql * 128 + d * 2) ^ ((ql & 7) << 4))) =
            (__bf16)(acc_o[df][qf][r] * dq[qf]);
      }
#pragma unroll
  for (int it = 0; it < 4; it++) {
    int ql = it * 8 + (lane >> 3), c = lane & 7;
    bf16x8 v = *(const bf16x8*)(PsW + ((ql * 128 + c * 16) ^ ((ql & 7) << 4)));
    int token = q0 + w * 32 + ql;
    *(bf16x8*)(AO + (((size_t)(b * 4096 + token)) << 10) + h * 64 + c * 8) = v;
  }
}

extern "C" void kernel_launch(void* const* d_in, const int* in_sizes, int n_in,
                              void* d_out, int out_size, void* d_ws, size_t ws_size,
                              hipStream_t stream) {
  const float* img  = (const float*)d_in[0];   // (2,4096,1024)
  const float* cnd  = (const float*)d_in[1];   // (2,1024,1024)
  const float* qnw  = (const float*)d_in[2];
  const float* kvnw = (const float*)d_in[3];
  const float* qhw  = (const float*)d_in[4];
  const float* khw  = (const float*)d_in[5];
  const float* qw   = (const float*)d_in[6];
  const float* qb   = (const float*)d_in[7];
  const float* kw   = (const float*)d_in[8];
  const float* kb   = (const float*)d_in[9];
  const float* vw   = (const float*)d_in[10];
  const float* vb   = (const float*)d_in[11];
  const float* ow   = (const float*)d_in[12];
  const float* ob   = (const float*)d_in[13];
  const float* alpha= (const float*)d_in[14];
  const float* icos = (const float*)d_in[15];  // (4096,64)
  const float* isin = (const float*)d_in[16];
  const float* ccos = (const float*)d_in[17];  // (1024,64)
  const float* csin = (const float*)d_in[18];
  float* out = (float*)d_out;

  __bf16* p = (__bf16*)d_ws;
  __bf16* wqb = p; p += 1048576;
  __bf16* wkb = p; p += 1048576;
  __bf16* wvb = p; p += 1048576;
  __bf16* wob = p; p += 1048576;
  __bf16* qn  = p; p += 8388608;   // (8192,1024)
  __bf16* kvn = p; p += 2097152;   // (2048,1024)
  __bf16* Qt  = p; p += 8388608;   // (8192,1024) -- reused later as AO
  __bf16* Kt  = p; p += 2097152;
  __bf16* Vt0 = p; p += 2097152;
  __bf16* Qr  = p; p += 8388608;   // (2,16,4096,64)
  __bf16* Kr  = p; p += 2097152;   // (2,16,1024,64)
  __bf16* Vtr = p; p += 2097152;   // (2,16,64,1024)
  __bf16* AO  = Qt;                // Qt dead after headnorm_rope(Q)

  rmsnorm_cast_kernel<<<8192, 256, 0, stream>>>(img, qnw, qn);
  rmsnorm_cast_kernel<<<2048, 256, 0, stream>>>(cnd, kvnw, kvn);
  cast_w_kernel<<<2048, 256, 0, stream>>>(qw, kw, vw, ow, wqb, wkb, wvb, wob);

  gemm_bt_kernel<0><<<dim3(64, 8), 256, 0, stream>>>(qn, wqb, qb, Qt, nullptr, nullptr);
  gemm_bt_kernel<0><<<dim3(16, 8), 256, 0, stream>>>(kvn, wkb, kb, Kt, nullptr, nullptr);
  gemm_bt_kernel<0><<<dim3(16, 8), 256, 0, stream>>>(kvn, wvb, vb, Vt0, nullptr, nullptr);

  headnorm_rope_kernel<<<4096, 256, 0, stream>>>(Qt, qhw, icos, isin, Qr, 12, 0.125f);
  headnorm_rope_kernel<<<1024, 256, 0, stream>>>(Kt, khw, ccos, csin, Kr, 10, 1.0f);
  v_transpose_kernel<<<512, 256, 0, stream>>>(Vt0, Vtr);

  attn_kernel<<<dim3(32, 32), 256, 0, stream>>>(Qr, Kr, Vtr, AO);

  gemm_bt_kernel<1><<<dim3(64, 8), 256, 0, stream>>>(AO, wob, ob, out, img, alpha);
}

// Round 2
// 217.929 us; speedup vs baseline: 1.2280x; 1.2280x over previous
//
#include <hip/hip_runtime.h>

typedef __bf16 bf16x8 __attribute__((ext_vector_type(8)));
typedef __bf16 bf16x4 __attribute__((ext_vector_type(4)));
typedef float  f32x4  __attribute__((ext_vector_type(4)));
typedef float  f32x16 __attribute__((ext_vector_type(16)));

#define DEVINL __device__ __forceinline__

DEVINL void gload_lds16(const void* g, void* l) {
  __builtin_amdgcn_global_load_lds((const __attribute__((address_space(1))) void*)g,
                                   (__attribute__((address_space(3))) void*)l, 16, 0, 0);
}

DEVINL unsigned pkbf(float a, float b) {
  union { __bf16 h[2]; unsigned u; } c;
  c.h[0] = (__bf16)a; c.h[1] = (__bf16)b;
  return c.u;
}

// ---------------- RMSNorm over hidden=1024 + cast to bf16 ----------------
__global__ __launch_bounds__(256) void rmsnorm_cast_kernel(
    const float* __restrict__ X, const float* __restrict__ W, __bf16* __restrict__ Y) {
  int row = blockIdx.x, tid = threadIdx.x;
  const float4* xr = (const float4*)(X + (size_t)row * 1024);
  float4 v = xr[tid];
  float ss = v.x * v.x + v.y * v.y + v.z * v.z + v.w * v.w;
#pragma unroll
  for (int m = 1; m < 64; m <<= 1) ss += __shfl_xor(ss, m);
  __shared__ float part[4];
  if ((tid & 63) == 0) part[tid >> 6] = ss;
  __syncthreads();
  float tot = part[0] + part[1] + part[2] + part[3];
  float rn = rsqrtf(tot * (1.0f / 1024.0f) + 1e-6f);
  float4 wv = ((const float4*)W)[tid];
  bf16x4 y;
  y[0] = (__bf16)(v.x * rn * wv.x);
  y[1] = (__bf16)(v.y * rn * wv.y);
  y[2] = (__bf16)(v.z * rn * wv.z);
  y[3] = (__bf16)(v.w * rn * wv.w);
  *(bf16x4*)(Y + (size_t)row * 1024 + tid * 4) = y;
}

// ---------------- cast 4 weight matrices (1024x1024 each) to bf16 ----------------
__global__ __launch_bounds__(256) void cast_w_kernel(
    const float* __restrict__ a, const float* __restrict__ b,
    const float* __restrict__ c, const float* __restrict__ d,
    __bf16* __restrict__ oa, __bf16* __restrict__ ob,
    __bf16* __restrict__ oc, __bf16* __restrict__ od) {
  int gid = blockIdx.x * 256 + threadIdx.x;
  int which = gid >> 17;
  size_t off = (size_t)(gid & 131071) * 8;
  const float* s = (which == 0) ? a : (which == 1) ? b : (which == 2) ? c : d;
  __bf16* o = (which == 0) ? oa : (which == 1) ? ob : (which == 2) ? oc : od;
  float4 v0 = *(const float4*)(s + off), v1 = *(const float4*)(s + off + 4);
  bf16x8 y;
  y[0] = (__bf16)v0.x; y[1] = (__bf16)v0.y; y[2] = (__bf16)v0.z; y[3] = (__bf16)v0.w;
  y[4] = (__bf16)v1.x; y[5] = (__bf16)v1.y; y[6] = (__bf16)v1.z; y[7] = (__bf16)v1.w;
  *(bf16x8*)(o + off) = y;
}

// ---------------- 128x128 tile bf16 GEMM, C = A @ W^T + bias (B^T layout) ----------------
template <int EPI>
__global__ __launch_bounds__(256) void gemm_bt_kernel(
    const __bf16* __restrict__ A, const __bf16* __restrict__ Bw,
    const float* __restrict__ bias, void* __restrict__ Cout,
    const float* __restrict__ resid, const float* __restrict__ alphap) {
  __shared__ __attribute__((aligned(16))) __bf16 As[128 * 32];
  __shared__ __attribute__((aligned(16))) __bf16 Bs[128 * 32];
  int tid = threadIdx.x, lane = tid & 63, w = tid >> 6, wr = w >> 1, wc = w & 1;
  int m0 = blockIdx.x * 128, n0 = blockIdx.y * 128;
  f32x4 z4 = {0.f, 0.f, 0.f, 0.f};
  f32x4 acc[4][4];
#pragma unroll
  for (int i = 0; i < 4; i++)
#pragma unroll
    for (int j = 0; j < 4; j++) acc[i][j] = z4;

  for (int k0 = 0; k0 < 1024; k0 += 32) {
#pragma unroll
    for (int i = 0; i < 2; i++) {
      int chunk = i * 256 + tid;
      int row = chunk >> 2, cc = chunk & 3;
      gload_lds16(A + (size_t)(m0 + row) * 1024 + k0 + cc * 8, (char*)As + i * 4096 + w * 1024);
      gload_lds16(Bw + (size_t)(n0 + row) * 1024 + k0 + cc * 8, (char*)Bs + i * 4096 + w * 1024);
    }
    __syncthreads();
    bf16x8 af[4], bfr[4];
#pragma unroll
    for (int m = 0; m < 4; m++) {
      int r = wr * 64 + m * 16 + (lane & 15);
      af[m] = *(const bf16x8*)((const char*)As + r * 64 + ((lane >> 4) << 4));
    }
#pragma unroll
    for (int n = 0; n < 4; n++) {
      int r = wc * 64 + n * 16 + (lane & 15);
      bfr[n] = *(const bf16x8*)((const char*)Bs + r * 64 + ((lane >> 4) << 4));
    }
#pragma unroll
    for (int m = 0; m < 4; m++)
#pragma unroll
      for (int n = 0; n < 4; n++)
        acc[m][n] = __builtin_amdgcn_mfma_f32_16x16x32_bf16(af[m], bfr[n], acc[m][n], 0, 0, 0);
    __syncthreads();
  }

  float aval = (EPI == 1) ? alphap[0] : 0.f;
#pragma unroll
  for (int m = 0; m < 4; m++)
#pragma unroll
    for (int n = 0; n < 4; n++) {
      int col = n0 + wc * 64 + n * 16 + (lane & 15);
      float bv = bias[col];
#pragma unroll
      for (int r = 0; r < 4; r++) {
        int row = m0 + wr * 64 + m * 16 + ((lane >> 4) << 2) + r;
        size_t idx = ((size_t)row << 10) + col;
        float v = acc[m][n][r] + bv;
        if (EPI == 0)
          ((__bf16*)Cout)[idx] = (__bf16)v;
        else
          ((float*)Cout)[idx] = resid[idx] + aval * v;
      }
    }
}

// ---------------- per-head RMSNorm + RoPE (+ optional scale), bf16 in/out ----------------
__global__ __launch_bounds__(256) void headnorm_rope_kernel(
    const __bf16* __restrict__ X, const float* __restrict__ HW,
    const float* __restrict__ COS, const float* __restrict__ SIN,
    __bf16* __restrict__ Y, int log2L, float scale) {
  int tid = threadIdx.x;
  int inst = blockIdx.x * 32 + (tid >> 3);
  int sub = tid & 7;
  int token = inst >> 4, h = inst & 15;
  int L = 1 << log2L;
  int b = token >> log2L, pos = token & (L - 1);
  const __bf16* xp = X + ((size_t)token << 10) + h * 64 + sub * 8;
  bf16x8 xv = *(const bf16x8*)xp;
  float xf[8];
#pragma unroll
  for (int i = 0; i < 8; i++) xf[i] = (float)xv[i];
  float ss = 0.f;
#pragma unroll
  for (int i = 0; i < 8; i++) ss += xf[i] * xf[i];
  ss += __shfl_xor(ss, 1);
  ss += __shfl_xor(ss, 2);
  ss += __shfl_xor(ss, 4);
  float rn = rsqrtf(ss * (1.0f / 64.0f) + 1e-6f);
  const float* hwp = HW + sub * 8;
  const float* cp = COS + ((size_t)pos << 6) + sub * 8;
  const float* sp = SIN + ((size_t)pos << 6) + sub * 8;
  float xn[8], o[8];
#pragma unroll
  for (int i = 0; i < 8; i++) xn[i] = xf[i] * rn * hwp[i];
#pragma unroll
  for (int i = 0; i < 8; i += 2) {
    float c0 = cp[i], c1 = cp[i + 1], s0 = sp[i], s1 = sp[i + 1];
    o[i] = (xn[i] * c0 - xn[i + 1] * s0) * scale;
    o[i + 1] = (xn[i + 1] * c1 + xn[i] * s1) * scale;
  }
  bf16x8 yv;
#pragma unroll
  for (int i = 0; i < 8; i++) yv[i] = (__bf16)o[i];
  *(bf16x8*)(Y + (((size_t)((b << 4) + h) << log2L) + pos) * 64 + sub * 8) = yv;
}

// ---------------- V transpose: (B*Lc,1024) token-major -> (B,16,64,Lc) ----------------
__global__ __launch_bounds__(256) void v_transpose_kernel(
    const __bf16* __restrict__ V, __bf16* __restrict__ Vt) {
  int bx = blockIdx.x;
  int bh = bx >> 4;
  int j0 = (bx & 15) * 64;
  int b = bh >> 4, h = bh & 15;
  int tid = threadIdx.x;
#pragma unroll
  for (int it = 0; it < 2; ++it) {
    int c = it * 256 + tid;
    int jl = c >> 3, d0 = (c & 7) * 8;
    bf16x8 v = *(const bf16x8*)(V + (size_t)(b * 1024 + j0 + jl) * 1024 + h * 64 + d0);
#pragma unroll
    for (int i = 0; i < 8; i++)
      Vt[((size_t)bh * 64 + d0 + i) * 1024 + j0 + jl] = v[i];
  }
}

// ---------------- flash attention, swapped-QK^T 32x32 structure ----------------
// Qr: (B,16,4096,64) bf16 pre-scaled by 0.125*log2(e) ; Kr: (B,16,1024,64) ;
// Vtr: (B,16,64,1024) ; AO: (B,4096,1024) bf16 token-major.
// Block: 4 waves, each owns 32 q-rows (lane&31 = q). Softmax is lane-local.
__global__ __launch_bounds__(256) void attn_kernel(
    const __bf16* __restrict__ Qr, const __bf16* __restrict__ Kr,
    const __bf16* __restrict__ Vtr, __bf16* __restrict__ AO) {
  int tid = threadIdx.x, lane = tid & 63, w = tid >> 6;
  int lq = lane & 31, hi = lane >> 5;
  int q0 = blockIdx.x * 128;
  int bh = blockIdx.y, b = bh >> 4, h = bh & 15;
  __shared__ __attribute__((aligned(16))) __bf16 Ks[2][64 * 64];
  __shared__ __attribute__((aligned(16))) __bf16 Vs[2][64 * 64];

  // Q fragments in registers: B-operand of S^T = K·Q^T. Lane's q = lq.
  bf16x8 qf[4];
  {
    const __bf16* qbase = Qr + ((size_t)bh * 4096 + q0 + w * 32 + lq) * 64 + hi * 8;
#pragma unroll
    for (int ds = 0; ds < 4; ds++) qf[ds] = *(const bf16x8*)(qbase + ds * 16);
  }

  const __bf16* kb0 = Kr + (size_t)bh * 1024 * 64;
  const __bf16* vb0 = Vtr + (size_t)bh * 64 * 1024;

  // stage tile 0 (XOR-swizzle via pre-swizzled global source, rule #21)
#pragma unroll
  for (int i = 0; i < 2; i++) {
    int c = i * 256 + tid, row = c >> 3, cl = (c & 7) ^ (row & 7);
    gload_lds16(kb0 + (size_t)row * 64 + cl * 8, (char*)Ks[0] + (i * 256 + w * 64) * 16);
    gload_lds16(vb0 + (size_t)row * 1024 + cl * 8, (char*)Vs[0] + (i * 256 + w * 64) * 16);
  }

  f32x16 accO[2];
#pragma unroll
  for (int r = 0; r < 16; r++) { accO[0][r] = 0.f; accO[1][r] = 0.f; }
  float mrun = -INFINITY, srun = 0.f;
  __syncthreads();

  int buf = 0;
  for (int t = 0; t < 16; t++) {
    if (t < 15) {
      const __bf16* kb = kb0 + (size_t)(t + 1) * 64 * 64;
      const __bf16* vb = vb0 + (t + 1) * 64;
#pragma unroll
      for (int i = 0; i < 2; i++) {
        int c = i * 256 + tid, row = c >> 3, cl = (c & 7) ^ (row & 7);
        gload_lds16(kb + (size_t)row * 64 + cl * 8, (char*)Ks[buf ^ 1] + (i * 256 + w * 64) * 16);
        gload_lds16(vb + (size_t)row * 1024 + cl * 8, (char*)Vs[buf ^ 1] + (i * 256 + w * 64) * 16);
      }
    }
    const char* kbase = (const char*)Ks[buf];
    const char* vbase = (const char*)Vs[buf];

    // S^T = K·Q^T : accS[kt] C-layout col=q(lq), row=k=crow(reg,hi)
    f32x16 accS[2];
#pragma unroll
    for (int r = 0; r < 16; r++) { accS[0][r] = 0.f; accS[1][r] = 0.f; }
#pragma unroll
    for (int kt = 0; kt < 2; kt++) {
      int row = kt * 32 + lq;
#pragma unroll
      for (int ds = 0; ds < 4; ds++) {
        bf16x8 kf = *(const bf16x8*)(kbase + row * 128 + (((ds << 1) + hi) ^ (row & 7)) * 16);
        accS[kt] = __builtin_amdgcn_mfma_f32_32x32x16_bf16(kf, qf[ds], accS[kt], 0, 0, 0);
      }
    }

    // lane-local row max over 32 regs, combine with partner lane (other 32 k)
    float pm = accS[0][0];
#pragma unroll
    for (int r = 1; r < 16; r++) pm = fmaxf(pm, accS[0][r]);
#pragma unroll
    for (int r = 0; r < 16; r++) pm = fmaxf(pm, accS[1][r]);
    pm = fmaxf(pm, __shfl_xor(pm, 32));

    // defer-max (T13): values are in log2 units, P bounded by 2^8
    bool defer = __all(pm - mrun <= 8.0f);
    if (!defer) {
      float mnew = fmaxf(mrun, pm);
      float sc = exp2f(mrun - mnew);
      srun *= sc;
      mrun = mnew;
      int sci = __float_as_int(sc);
#pragma unroll
      for (int r = 0; r < 16; r++) {
        int cr = (r & 3) + ((r >> 2) << 3) + (hi << 2);
        float scr = __int_as_float(__builtin_amdgcn_ds_bpermute(cr << 2, sci));
        accO[0][r] *= scr;
        accO[1][r] *= scr;
      }
    }

    // P = exp2(S - m), row sum
    float ssum = 0.f;
#pragma unroll
    for (int kt = 0; kt < 2; kt++)
#pragma unroll
      for (int r = 0; r < 16; r++) {
        float e = exp2f(accS[kt][r] - mrun);
        accS[kt][r] = e;
        ssum += e;
      }
    ssum += __shfl_xor(ssum, 32);
    srun += ssum;

    // build P A-frags in-register (T12 variant, shfl_xor(32) exchange)
    unsigned pa[4][4];
#pragma unroll
    for (int kt = 0; kt < 2; kt++)
#pragma unroll
      for (int s2 = 0; s2 < 2; s2++) {
        int rb = s2 * 8;
        unsigned u  = pkbf(accS[kt][rb + 0], accS[kt][rb + 1]);
        unsigned v2 = pkbf(accS[kt][rb + 2], accS[kt][rb + 3]);
        unsigned w2 = pkbf(accS[kt][rb + 4], accS[kt][rb + 5]);
        unsigned x2 = pkbf(accS[kt][rb + 6], accS[kt][rb + 7]);
        unsigned xu = __shfl_xor(u, 32), xv = __shfl_xor(v2, 32);
        unsigned xw = __shfl_xor(w2, 32), xx = __shfl_xor(x2, 32);
        int f = kt * 2 + s2;
        pa[f][0] = hi ? xw : u;
        pa[f][1] = hi ? xx : v2;
        pa[f][2] = hi ? w2 : xu;
        pa[f][3] = hi ? x2 : xv;
      }

    // O += P·V : A=P(32q x 16k), B=V(16k x 32d) from Vtr rows (contiguous k)
#pragma unroll
    for (int f = 0; f < 4; f++) {
      union { unsigned u[4]; bf16x8 v; } pf;
      pf.u[0] = pa[f][0]; pf.u[1] = pa[f][1]; pf.u[2] = pa[f][2]; pf.u[3] = pa[f][3];
#pragma unroll
      for (int dh = 0; dh < 2; dh++) {
        int row = dh * 32 + lq;
        bf16x8 vf = *(const bf16x8*)(vbase + row * 128 + (((f << 1) + hi) ^ (row & 7)) * 16);
        accO[dh] = __builtin_amdgcn_mfma_f32_32x32x16_bf16(pf.v, vf, accO[dh], 0, 0, 0);
      }
    }
    __syncthreads();
    buf ^= 1;
  }

  // epilogue: divide by row sum (transpose via bpermute), scalar bf16 stores
  float rinv = 1.0f / srun;
  int ri = __float_as_int(rinv);
  __bf16* aobase = AO + ((size_t)b * 4096) * 1024 + (size_t)h * 64;
#pragma unroll
  for (int r = 0; r < 16; r++) {
    int cr = (r & 3) + ((r >> 2) << 3) + (hi << 2);
    float rv = __int_as_float(__builtin_amdgcn_ds_bpermute(cr << 2, ri));
    int token = q0 + w * 32 + cr;
#pragma unroll
    for (int dh = 0; dh < 2; dh++)
      aobase[(size_t)token * 1024 + dh * 32 + lq] = (__bf16)(accO[dh][r] * rv);
  }
}

extern "C" void kernel_launch(void* const* d_in, const int* in_sizes, int n_in,
                              void* d_out, int out_size, void* d_ws, size_t ws_size,
                              hipStream_t stream) {
  const float* img  = (const float*)d_in[0];
  const float* cnd  = (const float*)d_in[1];
  const float* qnw  = (const float*)d_in[2];
  const float* kvnw = (const float*)d_in[3];
  const float* qhw  = (const float*)d_in[4];
  const float* khw  = (const float*)d_in[5];
  const float* qw   = (const float*)d_in[6];
  const float* qb   = (const float*)d_in[7];
  const float* kw   = (const float*)d_in[8];
  const float* kb   = (const float*)d_in[9];
  const float* vw   = (const float*)d_in[10];
  const float* vb   = (const float*)d_in[11];
  const float* ow   = (const float*)d_in[12];
  const float* ob   = (const float*)d_in[13];
  const float* alpha= (const float*)d_in[14];
  const float* icos = (const float*)d_in[15];
  const float* isin = (const float*)d_in[16];
  const float* ccos = (const float*)d_in[17];
  const float* csin = (const float*)d_in[18];
  float* out = (float*)d_out;

  __bf16* p = (__bf16*)d_ws;
  __bf16* wqb = p; p += 1048576;
  __bf16* wkb = p; p += 1048576;
  __bf16* wvb = p; p += 1048576;
  __bf16* wob = p; p += 1048576;
  __bf16* qn  = p; p += 8388608;
  __bf16* kvn = p; p += 2097152;
  __bf16* Qt  = p; p += 8388608;
  __bf16* Kt  = p; p += 2097152;
  __bf16* Vt0 = p; p += 2097152;
  __bf16* Qr  = p; p += 8388608;
  __bf16* Kr  = p; p += 2097152;
  __bf16* Vtr = p; p += 2097152;
  __bf16* AO  = Qt;  // Qt dead after headnorm_rope(Q)

  rmsnorm_cast_kernel<<<8192, 256, 0, stream>>>(img, qnw, qn);
  rmsnorm_cast_kernel<<<2048, 256, 0, stream>>>(cnd, kvnw, kvn);
  cast_w_kernel<<<2048, 256, 0, stream>>>(qw, kw, vw, ow, wqb, wkb, wvb, wob);

  gemm_bt_kernel<0><<<dim3(64, 8), 256, 0, stream>>>(qn, wqb, qb, Qt, nullptr, nullptr);
  gemm_bt_kernel<0><<<dim3(16, 8), 256, 0, stream>>>(kvn, wkb, kb, Kt, nullptr, nullptr);
  gemm_bt_kernel<0><<<dim3(16, 8), 256, 0, stream>>>(kvn, wvb, vb, Vt0, nullptr, nullptr);

  // Q pre-scaled by 0.125*log2(e): attention works in log2 domain (exp2 direct)
  headnorm_rope_kernel<<<4096, 256, 0, stream>>>(Qt, qhw, icos, isin, Qr, 12, 0.125f * 1.44269504f);
  headnorm_rope_kernel<<<1024, 256, 0, stream>>>(Kt, khw, ccos, csin, Kr, 10, 1.0f);
  v_transpose_kernel<<<512, 256, 0, stream>>>(Vt0, Vtr);

  attn_kernel<<<dim3(32, 32), 256, 0, stream>>>(Qr, Kr, Vtr, AO);

  gemm_bt_kernel<1><<<dim3(64, 8), 256, 0, stream>>>(AO, wob, ob, out, img, alpha);
}